// Round 9
// baseline (174.782 us; speedup 1.0000x reference)
//
#include <hip/hip_runtime.h>
#include <math.h>

// CrossAttention B=2, Sq=Sk=2048, H=16, Hkv=4, D=64, fp32 io.
// R9: R5's proven 16x16x32 QT=64 pipeline, but QK^T computed as S^T = K*Q^T:
// C-layout then hands each lane 4 consecutive KEYS per qrow, so P stores are
// packed ds_write_b64 and PV A-frags read back as b128 (kills R5's 16 scalar
// u16 stores/lane/tile + their conflicts). Ballot pad mask (no padf LDS).
// Fixed-shift exp2 softmax, l via ones-MFMA, 66-tile/slot balance, fixup
// for degenerate rows (R < first_kept) fused as blocks 0..31.

typedef __bf16 bf16x4 __attribute__((ext_vector_type(4)));
typedef __bf16 bf16x8 __attribute__((ext_vector_type(8)));
typedef float floatx4 __attribute__((ext_vector_type(4)));

#define B_ 2
#define SQ 2048
#define SK 2048
#define H_ 16
#define HKV 4
#define D_ 64
#define QT 64
#define KT 64
#define PADK 72             // 144B rows; proven pattern (R5: conflicts low)
#define KVROW 512           // floats per (b,s) slot: 2*HKV*D
#define NEGV (-10000.0f)
#define QSCL 0.18033688f    // 0.125 * log2(e)
#define EBIAS 17.3123405f   // fixed softmax shift (exp2 space)

__global__ __launch_bounds__(256, 4)
void attn_kernel(const float* __restrict__ q,
                 const float* __restrict__ kv,
                 const int* __restrict__ mask,
                 float* __restrict__ out)
{
    __shared__ union {
        struct {
            __bf16 Kt[KT][PADK];        // [key][d]
            __bf16 Vt[D_][PADK];        // [d][key]
            __bf16 Pt[4][16][PADK];     // [wave][qrow][key]  (P, packed)
        } m;
        struct { float part[4][64]; float w[4][64]; } f;   // fixup scratch
    } u;
    __shared__ int s_first;

    const int tid  = threadIdx.x;
    const int wave = tid >> 6;
    const int lane = tid & 63;
    const int col  = lane & 15;
    const int quad = lane >> 4;

    if (blockIdx.x < 32) {
        // ================= fixup role: rows R < first_kept[b] ===============
        const int bh = (int)blockIdx.x;
        const int b = bh >> 4, h = bh & 15, hkv = h >> 2;
        if (tid == 0) s_first = SK;
        __syncthreads();
        int local = SK;
        for (int s = tid; s < SK; s += 256)
            if (mask[b * SK + s]) local = min(local, s);
        atomicMin(&s_first, local);
        __syncthreads();
        const int nfirst = s_first;
        if (nfirst == 0) return;

        const float* kvb = kv + (size_t)b * SK * KVROW + hkv * D_;
        const float* vvb = kvb + HKV * D_;
        {
            float a0=0,a1=0,a2=0,a3=0,a4=0,a5=0,a6=0,a7=0;
            const int s0 = wave * 512;
            for (int s = s0; s < s0 + 512; s += 8) {
                a0 += vvb[(size_t)(s+0)*KVROW + lane];
                a1 += vvb[(size_t)(s+1)*KVROW + lane];
                a2 += vvb[(size_t)(s+2)*KVROW + lane];
                a3 += vvb[(size_t)(s+3)*KVROW + lane];
                a4 += vvb[(size_t)(s+4)*KVROW + lane];
                a5 += vvb[(size_t)(s+5)*KVROW + lane];
                a6 += vvb[(size_t)(s+6)*KVROW + lane];
                a7 += vvb[(size_t)(s+7)*KVROW + lane];
            }
            u.f.part[wave][lane] = ((a0+a1)+(a2+a3)) + ((a4+a5)+(a6+a7));
        }
        __syncthreads();
        const float vtotal = u.f.part[0][lane] + u.f.part[1][lane]
                           + u.f.part[2][lane] + u.f.part[3][lane];

        for (int R = wave; R < nfirst; R += 4) {
            const float* qrow = q + (((size_t)b * SQ + R) * H_ + h) * D_;
            float mymax = -3.4e38f;
            for (int s = lane; s <= R; s += 64) {
                const float* kp = kvb + (size_t)s * KVROW;
                float dt = 0.f;
                for (int d = 0; d < D_; ++d) dt += qrow[d] * kp[d];
                mymax = fmaxf(mymax, dt * 0.125f + NEGV);
            }
#pragma unroll
            for (int off = 32; off >= 1; off >>= 1)
                mymax = fmaxf(mymax, __shfl_xor(mymax, off, 64));
            const float M = (R < SK - 1) ? fmaxf(mymax, NEGV) : mymax;
            float lsum = 0.f, oacc = 0.f, pref = 0.f;
            for (int s0 = 0; s0 <= R; s0 += 64) {
                int s = s0 + lane;
                float w = 0.f;
                if (s <= R) {
                    const float* kp = kvb + (size_t)s * KVROW;
                    float dt = 0.f;
                    for (int d = 0; d < D_; ++d) dt += qrow[d] * kp[d];
                    w = __expf(dt * 0.125f + NEGV - M);
                    lsum += w;
                }
                u.f.w[wave][lane] = w;   // wave-private, in-order
                const int nk = (R - s0 + 1 < 64) ? (R - s0 + 1) : 64;
                for (int j = 0; j < nk; ++j) {
                    const float vj = vvb[(size_t)(s0 + j) * KVROW + lane];
                    oacc += u.f.w[wave][j] * vj;
                    pref += vj;
                }
            }
#pragma unroll
            for (int off = 32; off >= 1; off >>= 1)
                lsum += __shfl_xor(lsum, off, 64);
            const float wn   = __expf(NEGV - M);
            const float ltot = lsum + wn * (float)(SK - 1 - R);
            out[(((size_t)b * SQ + R) * H_ + h) * D_ + lane] =
                (oacc + wn * (vtotal - pref)) / ltot;
        }
        return;
    }

    // ================= main attention role ==================================
    const int id = (int)blockIdx.x - 32;
    const int bh = id & 31;
    const int y  = id >> 5;               // 0..31
    const int kg = y >> 3, jj = y & 7;    // quad {31-j, j, 23-j, 8+j}: 66 tiles
    const int qt = (kg == 0) ? 31 - jj : (kg == 1) ? jj : (kg == 2) ? 23 - jj : 8 + jj;
    const int b = bh >> 4, h = bh & 15, hkv = h >> 2;
    const int q0 = qt * QT;
    const int qw = q0 + wave * 16;
    const int qrow_g = qw + col;          // this lane's qrow (S^T column)

    // ---- Q^T B-fragments: B[k=d=kc*32+quad*8+j][n=qrow=col], exp2-scaled ----
    bf16x8 bq[2];
    {
        const float* qp = q + (((size_t)b * SQ + qrow_g) * H_ + h) * D_ + quad * 8;
#pragma unroll
        for (int kc = 0; kc < 2; ++kc) {
            const float* p = qp + kc * 32;
#pragma unroll
            for (int j = 0; j < 8; ++j) bq[kc][j] = (__bf16)(p[j] * QSCL);
        }
    }

    bf16x8 vone;
#pragma unroll
    for (int j = 0; j < 8; ++j) vone[j] = (__bf16)1.0f;

    floatx4 o[4];
    floatx4 l_acc = (floatx4){0.f, 0.f, 0.f, 0.f};
#pragma unroll
    for (int dj = 0; dj < 4; ++dj) o[dj] = (floatx4){0.f, 0.f, 0.f, 0.f};

    const int kkey = tid >> 4;
    const int kd   = (tid & 15) * 4;
    const int vkey = (tid & 15) * 4;
    const int vd   = (tid >> 4) * 4;

    const float* kvb = kv + (size_t)b * SK * KVROW + hkv * D_;

    float4 kreg[4], vreg[4];
    int mreg = 0;

    auto prefetch = [&](int kt) {
        const float* kb = kvb + (size_t)kt * KT * KVROW;
#pragma unroll
        for (int i = 0; i < 4; ++i)
            kreg[i] = *(const float4*)(kb + (kkey + 16 * i) * KVROW + kd);
        const float* vb = kb + HKV * D_;
#pragma unroll
        for (int i = 0; i < 4; ++i)
            vreg[i] = *(const float4*)(vb + (vkey + i) * KVROW + vd);
        mreg = mask[b * SK + kt * KT + lane];
    };

    auto stage = [&]() {
#pragma unroll
        for (int i = 0; i < 4; ++i) {
            bf16x4 t = { (__bf16)kreg[i].x, (__bf16)kreg[i].y,
                         (__bf16)kreg[i].z, (__bf16)kreg[i].w };
            *(bf16x4*)&u.m.Kt[kkey + 16 * i][kd] = t;
        }
        const float* vf = (const float*)vreg;
#pragma unroll
        for (int j = 0; j < 4; ++j) {
            bf16x4 t = { (__bf16)vf[0*4+j], (__bf16)vf[1*4+j],
                         (__bf16)vf[2*4+j], (__bf16)vf[3*4+j] };
            *(bf16x4*)&u.m.Vt[vd + j][vkey] = t;
        }
    };

    const int nkt = qt + 1;
    prefetch(0);

    for (int kt = 0; kt < nkt; ++kt) {
        stage();
        const unsigned long long kept = __ballot(mreg != 0);  // tile kt's mask
        __syncthreads();
        if (kt + 1 < nkt) prefetch(kt + 1);   // lands during compute

        const int k0 = kt * KT;
        const bool dg = (kt == qt);

        // ---- S^T = K * Q^T : C[m=key=kj*16+quad*4+r][n=qrow=col] ----
        floatx4 cst[4];
#pragma unroll
        for (int kj = 0; kj < 4; ++kj) {
            cst[kj] = (floatx4){0.f, 0.f, 0.f, 0.f};
#pragma unroll
            for (int kc = 0; kc < 2; ++kc) {
                bf16x8 ak = *(const bf16x8*)&u.m.Kt[kj * 16 + col][kc * 32 + quad * 8];
                cst[kj] = __builtin_amdgcn_mfma_f32_16x16x32_bf16(ak, bq[kc], cst[kj], 0, 0, 0);
            }
        }
        // ---- mask + exp2 + PACKED P store (4 x ds_write_b64) ----
#pragma unroll
        for (int kj = 0; kj < 4; ++kj) {
            const int keyb = kj * 16 + quad * 4;          // key of r=0
            const unsigned bits = (unsigned)(kept >> keyb);
            bf16x4 pk;
#pragma unroll
            for (int r = 0; r < 4; ++r) {
                float p = __builtin_amdgcn_exp2f(cst[kj][r] - EBIAS);
                if (!((bits >> r) & 1u)) p = 0.f;                 // pad: exact
                if (dg && (k0 + keyb + r > qrow_g)) p = 0.f;      // causal
                pk[r] = (__bf16)p;
            }
            *(bf16x4*)&u.m.Pt[wave][col][keyb] = pk;
        }
        // ---- P @ [V | ones] (wave-private LDS round-trip, b128 reads) ----
        bf16x8 ap[2];
#pragma unroll
        for (int kc = 0; kc < 2; ++kc)
            ap[kc] = *(const bf16x8*)&u.m.Pt[wave][col][kc * 32 + quad * 8];
#pragma unroll
        for (int kc = 0; kc < 2; ++kc)
            l_acc = __builtin_amdgcn_mfma_f32_16x16x32_bf16(ap[kc], vone, l_acc, 0, 0, 0);
#pragma unroll
        for (int dj = 0; dj < 4; ++dj)
#pragma unroll
            for (int kc = 0; kc < 2; ++kc) {
                bf16x8 bv = *(const bf16x8*)&u.m.Vt[dj * 16 + col][kc * 32 + quad * 8];
                o[dj] = __builtin_amdgcn_mfma_f32_16x16x32_bf16(ap[kc], bv, o[dj], 0, 0, 0);
            }
        __syncthreads();
    }

    // ---- epilogue: normalize + store; l==0 rows written by fixup ----
#pragma unroll
    for (int r = 0; r < 4; ++r) {
        const float l = l_acc[r];
        if (l > 0.f) {
            const float inv = 1.0f / l;
            const int row = qw + quad * 4 + r;
            float* op = out + (((size_t)b * SQ + row) * H_ + h) * D_ + col;
#pragma unroll
            for (int dj = 0; dj < 4; ++dj)
                op[dj * 16] = o[dj][r] * inv;
        }
    }
}

extern "C" void kernel_launch(void* const* d_in, const int* in_sizes, int n_in,
                              void* d_out, int out_size, void* d_ws, size_t ws_size,
                              hipStream_t stream) {
    const float* q   = (const float*)d_in[0];
    const float* kv  = (const float*)d_in[1];
    const int* mask  = (const int*)d_in[2];
    float* out       = (float*)d_out;
    attn_kernel<<<dim3(32 + 1024), 256, 0, stream>>>(q, kv, mask, out);
}

// Round 10
// 127.040 us; speedup vs baseline: 1.3758x; 1.3758x over previous
//
#include <hip/hip_runtime.h>
#include <math.h>

// CrossAttention B=2, Sq=Sk=2048, H=16, Hkv=4, D=64, fp32 io.
// R10: R5's measured-optimal main loop VERBATIM (S = Q*K^T, A=Q-regs,
// B=K-LDS, scalar u16 P stores -> measured-lowest bank conflicts), plus the
// two exonerated improvements: fixup fused as blocks 0..31 (removes ~25us
// of serialized second dispatch) and ballot pad-mask (no padf LDS array).
// Fixed-shift exp2 softmax, l via ones-MFMA, 66-tile/slot balance.

typedef __bf16 bf16x4 __attribute__((ext_vector_type(4)));
typedef __bf16 bf16x8 __attribute__((ext_vector_type(8)));
typedef float floatx4 __attribute__((ext_vector_type(4)));

#define B_ 2
#define SQ 2048
#define SK 2048
#define H_ 16
#define HKV 4
#define D_ 64
#define QT 64
#define KT 64
#define PADLD 72            // 144B rows (R5-measured layout)
#define KVROW 512           // floats per (b,s) slot: 2*HKV*D
#define NEGV (-10000.0f)
#define QSCL 0.18033688f    // 0.125 * log2(e)
#define EBIAS 17.3123405f   // fixed softmax shift (exp2 space)

__global__ __launch_bounds__(256, 4)
void attn_kernel(const float* __restrict__ q,
                 const float* __restrict__ kv,
                 const int* __restrict__ mask,
                 float* __restrict__ out)
{
    __shared__ alignas(16) __bf16 Kt[KT][PADLD];
    __shared__ alignas(16) __bf16 Vt[D_][PADLD];
    __shared__ alignas(16) __bf16 Pl[4][16][PADLD];
    __shared__ float fpart[4][64];          // fixup-only
    __shared__ float fw[4][64];             // fixup-only
    __shared__ int s_first;                 // fixup-only

    const int tid  = threadIdx.x;
    const int wave = tid >> 6;
    const int lane = tid & 63;
    const int col  = lane & 15;
    const int quad = lane >> 4;

    if (blockIdx.x < 32) {
        // ================= fixup role: rows R < first_kept[b] ===============
        const int bh = (int)blockIdx.x;
        const int b = bh >> 4, h = bh & 15, hkv = h >> 2;
        if (tid == 0) s_first = SK;
        __syncthreads();
        int local = SK;
        for (int s = tid; s < SK; s += 256)
            if (mask[b * SK + s]) local = min(local, s);
        atomicMin(&s_first, local);
        __syncthreads();
        const int nfirst = s_first;
        if (nfirst == 0) return;

        const float* kvb = kv + (size_t)b * SK * KVROW + hkv * D_;
        const float* vvb = kvb + HKV * D_;
        {
            float a0=0,a1=0,a2=0,a3=0,a4=0,a5=0,a6=0,a7=0;
            const int s0 = wave * 512;
            for (int s = s0; s < s0 + 512; s += 8) {
                a0 += vvb[(size_t)(s+0)*KVROW + lane];
                a1 += vvb[(size_t)(s+1)*KVROW + lane];
                a2 += vvb[(size_t)(s+2)*KVROW + lane];
                a3 += vvb[(size_t)(s+3)*KVROW + lane];
                a4 += vvb[(size_t)(s+4)*KVROW + lane];
                a5 += vvb[(size_t)(s+5)*KVROW + lane];
                a6 += vvb[(size_t)(s+6)*KVROW + lane];
                a7 += vvb[(size_t)(s+7)*KVROW + lane];
            }
            fpart[wave][lane] = ((a0+a1)+(a2+a3)) + ((a4+a5)+(a6+a7));
        }
        __syncthreads();
        const float vtotal = fpart[0][lane] + fpart[1][lane]
                           + fpart[2][lane] + fpart[3][lane];

        for (int R = wave; R < nfirst; R += 4) {
            const float* qrow = q + (((size_t)b * SQ + R) * H_ + h) * D_;
            float mymax = -3.4e38f;
            for (int s = lane; s <= R; s += 64) {
                const float* kp = kvb + (size_t)s * KVROW;
                float dt = 0.f;
                for (int d = 0; d < D_; ++d) dt += qrow[d] * kp[d];
                mymax = fmaxf(mymax, dt * 0.125f + NEGV);
            }
#pragma unroll
            for (int off = 32; off >= 1; off >>= 1)
                mymax = fmaxf(mymax, __shfl_xor(mymax, off, 64));
            const float M = (R < SK - 1) ? fmaxf(mymax, NEGV) : mymax;
            float lsum = 0.f, oacc = 0.f, pref = 0.f;
            for (int s0 = 0; s0 <= R; s0 += 64) {
                int s = s0 + lane;
                float w = 0.f;
                if (s <= R) {
                    const float* kp = kvb + (size_t)s * KVROW;
                    float dt = 0.f;
                    for (int d = 0; d < D_; ++d) dt += qrow[d] * kp[d];
                    w = __expf(dt * 0.125f + NEGV - M);
                    lsum += w;
                }
                fw[wave][lane] = w;   // wave-private, in-order
                const int nk = (R - s0 + 1 < 64) ? (R - s0 + 1) : 64;
                for (int j = 0; j < nk; ++j) {
                    const float vj = vvb[(size_t)(s0 + j) * KVROW + lane];
                    oacc += fw[wave][j] * vj;
                    pref += vj;
                }
            }
#pragma unroll
            for (int off = 32; off >= 1; off >>= 1)
                lsum += __shfl_xor(lsum, off, 64);
            const float wn   = __expf(NEGV - M);
            const float ltot = lsum + wn * (float)(SK - 1 - R);
            out[(((size_t)b * SQ + R) * H_ + h) * D_ + lane] =
                (oacc + wn * (vtotal - pref)) / ltot;
        }
        return;
    }

    // ================= main attention role (R5 verbatim) ====================
    const int id = (int)blockIdx.x - 32;
    const int bh = id & 31;
    const int y  = id >> 5;               // 0..31
    const int kg = y >> 3, jj = y & 7;    // quad {31-j, j, 23-j, 8+j}: 66 tiles
    const int qt = (kg == 0) ? 31 - jj : (kg == 1) ? jj : (kg == 2) ? 23 - jj : 8 + jj;
    const int b = bh >> 4, h = bh & 15, hkv = h >> 2;
    const int q0 = qt * QT;
    const int qw = q0 + wave * 16;

    // ---- Q A-fragments, pre-scaled into exp2 space ----
    bf16x8 aq[2];
    {
        const int row = qw + col;
        const float* qp = q + (((size_t)b * SQ + row) * H_ + h) * D_ + quad * 8;
#pragma unroll
        for (int kc = 0; kc < 2; ++kc) {
            const float* p = qp + kc * 32;
#pragma unroll
            for (int j = 0; j < 8; ++j) aq[kc][j] = (__bf16)(p[j] * QSCL);
        }
    }

    bf16x8 vone;
#pragma unroll
    for (int j = 0; j < 8; ++j) vone[j] = (__bf16)1.0f;

    floatx4 o[4];
    floatx4 l_acc = (floatx4){0.f, 0.f, 0.f, 0.f};
#pragma unroll
    for (int dj = 0; dj < 4; ++dj) o[dj] = (floatx4){0.f, 0.f, 0.f, 0.f};

    const int kkey = tid >> 4;
    const int kd   = (tid & 15) * 4;
    const int vkey = (tid & 15) * 4;
    const int vd   = (tid >> 4) * 4;

    const float* kvb = kv + (size_t)b * SK * KVROW + hkv * D_;

    float4 kreg[4], vreg[4];
    int mreg = 0;

    auto prefetch = [&](int kt) {
        const float* kb = kvb + (size_t)kt * KT * KVROW;
#pragma unroll
        for (int i = 0; i < 4; ++i)
            kreg[i] = *(const float4*)(kb + (kkey + 16 * i) * KVROW + kd);
        const float* vb = kb + HKV * D_;
#pragma unroll
        for (int i = 0; i < 4; ++i)
            vreg[i] = *(const float4*)(vb + (vkey + i) * KVROW + vd);
        mreg = mask[b * SK + kt * KT + lane];
    };

    auto stage = [&]() {
#pragma unroll
        for (int i = 0; i < 4; ++i) {
            bf16x4 t = { (__bf16)kreg[i].x, (__bf16)kreg[i].y,
                         (__bf16)kreg[i].z, (__bf16)kreg[i].w };
            *(bf16x4*)&Kt[kkey + 16 * i][kd] = t;
        }
        const float* vf = (const float*)vreg;
#pragma unroll
        for (int j = 0; j < 4; ++j) {
            bf16x4 t = { (__bf16)vf[0*4+j], (__bf16)vf[1*4+j],
                         (__bf16)vf[2*4+j], (__bf16)vf[3*4+j] };
            *(bf16x4*)&Vt[vd + j][vkey] = t;
        }
    };

    const int nkt = qt + 1;
    prefetch(0);

    for (int kt = 0; kt < nkt; ++kt) {
        stage();
        const unsigned long long kept = __ballot(mreg != 0);  // tile kt's mask
        __syncthreads();
        if (kt + 1 < nkt) prefetch(kt + 1);   // lands during compute

        // ---- QK^T (exp2 space) ----
        floatx4 c[4];
#pragma unroll
        for (int kj = 0; kj < 4; ++kj) {
            c[kj] = (floatx4){0.f, 0.f, 0.f, 0.f};
#pragma unroll
            for (int kc = 0; kc < 2; ++kc) {
                bf16x8 bk = *(const bf16x8*)&Kt[kj * 16 + col][kc * 32 + quad * 8];
                c[kj] = __builtin_amdgcn_mfma_f32_16x16x32_bf16(aq[kc], bk, c[kj], 0, 0, 0);
            }
        }
        // ---- mask (ballot bit-test) + exp2 + P store (R5 pattern) ----
        const bool dg = (kt == qt);
        const int rowl = wave * 16 + quad * 4;
#pragma unroll
        for (int kj = 0; kj < 4; ++kj) {
            const int keyl = kj * 16 + col;
            const bool keep = (kept >> keyl) & 1ull;
#pragma unroll
            for (int r = 0; r < 4; ++r) {
                float p = __builtin_amdgcn_exp2f(c[kj][r] - EBIAS);
                if (!keep) p = 0.f;                       // pad: exact
                if (dg && keyl > rowl + r) p = 0.f;       // causal
                Pl[wave][quad * 4 + r][keyl] = (__bf16)p;
            }
        }
        // ---- P @ [V | ones] (wave-private LDS round-trip, no barrier) ----
        bf16x8 ap[2];
#pragma unroll
        for (int kc = 0; kc < 2; ++kc)
            ap[kc] = *(const bf16x8*)&Pl[wave][col][kc * 32 + quad * 8];
#pragma unroll
        for (int kc = 0; kc < 2; ++kc)
            l_acc = __builtin_amdgcn_mfma_f32_16x16x32_bf16(ap[kc], vone, l_acc, 0, 0, 0);
#pragma unroll
        for (int dj = 0; dj < 4; ++dj)
#pragma unroll
            for (int kc = 0; kc < 2; ++kc) {
                bf16x8 bv = *(const bf16x8*)&Vt[dj * 16 + col][kc * 32 + quad * 8];
                o[dj] = __builtin_amdgcn_mfma_f32_16x16x32_bf16(ap[kc], bv, o[dj], 0, 0, 0);
            }
        __syncthreads();
    }

    // ---- epilogue: normalize + store; l==0 rows written by fixup role ----
#pragma unroll
    for (int r = 0; r < 4; ++r) {
        const float l = l_acc[r];
        if (l > 0.f) {
            const float inv = 1.0f / l;
            const int row = qw + quad * 4 + r;
            float* op = out + (((size_t)b * SQ + row) * H_ + h) * D_ + col;
#pragma unroll
            for (int dj = 0; dj < 4; ++dj)
                op[dj * 16] = o[dj][r] * inv;
        }
    }
}

extern "C" void kernel_launch(void* const* d_in, const int* in_sizes, int n_in,
                              void* d_out, int out_size, void* d_ws, size_t ws_size,
                              hipStream_t stream) {
    const float* q   = (const float*)d_in[0];
    const float* kv  = (const float*)d_in[1];
    const int* mask  = (const int*)d_in[2];
    float* out       = (float*)d_out;
    attn_kernel<<<dim3(32 + 1024), 256, 0, stream>>>(q, kv, mask, out);
}